// Round 6
// baseline (167.142 us; speedup 1.0000x reference)
//
#include <hip/hip_runtime.h>
#include <hip/hip_bf16.h>
#include <stdint.h>
#include <string.h>

typedef __attribute__((ext_vector_type(8))) short short8;   // 8 bf16 (4 VGPRs) MFMA operand
typedef __attribute__((ext_vector_type(4))) float floatx4;  // MFMA accumulator

#define NPTS 256   // points per group
#define DIM  256   // feature dim
#define TILE 128   // output tile per block
#define BK   32    // K-step
#define NIT  (DIM / BK)          // 8 K-iterations
#define LDSS 40    // LDS row stride in bf16 elems (80 B; read pattern 2-way = free)

// Workgroup barrier WITHOUT the vmcnt(0) drain __syncthreads() forces:
// LDS producer->consumer only needs lgkmcnt(0); our in-flight global
// prefetches live in private VGPRs and must NOT be drained here.
#define LDS_BARRIER() asm volatile("s_waitcnt lgkmcnt(0)\n\ts_barrier" ::: "memory")

// packed fp32->bf16 RNE convert; also accumulates squared sum of the
// ROUNDED values (consistent metric between Gram term and norms).
static __device__ __forceinline__ uint32_t cvtsq2(float a, float b, float& s) {
    __hip_bfloat162 h = __float22bfloat162_rn(float2{a, b});
    uint32_t d;
    memcpy(&d, &h, 4);
    const float lo = __builtin_bit_cast(float, d << 16);
    const float hi = __builtin_bit_cast(float, d & 0xFFFF0000u);
    s += lo * lo + hi * hi;
    return d;
}
static __device__ __forceinline__ uint4 cvt8(const float4 u, const float4 v, float& s) {
    uint4 r;
    r.x = cvtsq2(u.x, u.y, s); r.y = cvtsq2(u.z, u.w, s);
    r.z = cvtsq2(v.x, v.y, s); r.w = cvtsq2(v.z, v.w, s);
    return r;
}

// ---------------------------------------------------------------------------
// grid = 10*G linear blocks, XCD-swizzled so all 10 tiles of a group share an
// XCD (L2 reuse). t 0..3 = XY (w=+1), 4..6 = XX upper-tri (w=-0.5/-1/-0.5,
// off-diag tile double-counted via w), 7..9 = YY upper-tri.
// t in {4,6,7,9} are diagonal tiles: A-stripe == B-stripe -> B side skipped
// entirely (frags read from As, cnorm = rnorm).
// ---------------------------------------------------------------------------
__global__ __launch_bounds__(512, 4)
void mmd_pipe(const float* __restrict__ X, const float* __restrict__ Y,
              float* __restrict__ out, float scale, int G) {
    // ---- block -> (group, tile) decode with XCD swizzle ----
    int g, t;
    const int f = blockIdx.x;
    if ((G & 7) == 0) { const int xcd = f & 7, j = f >> 3; g = (j / 10) * 8 + xcd; t = j % 10; }
    else              { g = f / 10; t = f % 10; }

    int ptype, ti, tj; float w;
    if (t < 4)      { ptype = 0; ti = t >> 1; tj = t & 1; w = 1.0f; }
    else if (t < 7) { int u = t - 4; ptype = 1; ti = (u == 2); tj = (u >= 1); w = (u == 1) ? -1.0f : -0.5f; }
    else            { int u = t - 7; ptype = 2; ti = (u == 2); tj = (u >= 1); w = (u == 1) ? -1.0f : -0.5f; }

    const float *Pf, *Qf;
    if (ptype == 0)      { Pf = X; Qf = Y; }
    else if (ptype == 1) { Pf = X; Qf = X; }
    else                 { Pf = Y; Qf = Y; }
    const bool symdiag = (ptype != 0) && (ti == tj);

    const size_t prow0 = (size_t)g * NPTS + (size_t)ti * TILE;
    const size_t qrow0 = (size_t)g * NPTS + (size_t)tj * TILE;

    __shared__ __align__(16) uint16_t As[2][TILE * LDSS];  // 2 x 10 KB
    __shared__ __align__(16) uint16_t Bs[2][TILE * LDSS];
    __shared__ float rnorm[TILE];
    __shared__ float cnorm[TILE];
    __shared__ float wpart[8];

    const int tid  = threadIdx.x;          // 0..511
    const int lane = tid & 63;
    const int wv   = tid >> 6;             // 0..7
    const int quad = lane >> 4;
    const int l15  = lane & 15;
    const int rowbase = (wv & 3) * 32;     // wave's 32-row stripe
    const int colbase = (wv >> 2) * 64;    // wave's 64-col stripe

    // ---- producer geometry: thread t stages row t>>2, float cols (t&3)*8..+8
    const int prow = tid >> 2;
    const int pcol = (tid & 3) * 8;
    const float* gA = Pf + (prow0 + prow) * DIM + pcol;
    const float* gB = Qf + (qrow0 + prow) * DIM + pcol;
    const int woff = prow * LDSS + pcol;   // bf16-elem offset in LDS slice

    floatx4 acc[2][4];
    #pragma unroll
    for (int i = 0; i < 2; ++i)
        #pragma unroll
        for (int j = 0; j < 4; ++j) acc[i][j] = (floatx4)0.0f;

    float sqp = 0.0f, sqq = 0.0f;          // this thread's partial row norms

    // ---- prologue: slice 0 -> LDS[0]; start loading slice 1 ----
    float4 ra0 = *(const float4*)(gA);
    float4 ra1 = *(const float4*)(gA + 4);
    float4 rb0, rb1;
    if (!symdiag) { rb0 = *(const float4*)(gB); rb1 = *(const float4*)(gB + 4); }
    {
        const uint4 pa = cvt8(ra0, ra1, sqp);
        *(uint4*)&As[0][woff] = pa;
        if (!symdiag) {
            const uint4 pb = cvt8(rb0, rb1, sqq);
            *(uint4*)&Bs[0][woff] = pb;
        }
    }
    ra0 = *(const float4*)(gA + BK);
    ra1 = *(const float4*)(gA + BK + 4);
    if (!symdiag) {
        rb0 = *(const float4*)(gB + BK);
        rb1 = *(const float4*)(gB + BK + 4);
    }

    // ---- main pipeline: 1 lgkm-only barrier/iter, write-ahead-1, load-ahead-2
    #pragma unroll
    for (int it = 0; it < NIT; ++it) {
        const int b = it & 1;
        LDS_BARRIER();                      // LDS[b] (written last iter) visible

        if (it < NIT - 1) {                 // write slice it+1 into LDS[b^1]
            const uint4 pa = cvt8(ra0, ra1, sqp);
            *(uint4*)&As[b ^ 1][woff] = pa;
            if (!symdiag) {
                const uint4 pb = cvt8(rb0, rb1, sqq);
                *(uint4*)&Bs[b ^ 1][woff] = pb;
            }
        }
        if (it < NIT - 2) {                 // start loading slice it+2
            const int k0 = (it + 2) * BK;
            ra0 = *(const float4*)(gA + k0);
            ra1 = *(const float4*)(gA + k0 + 4);
            if (!symdiag) {
                rb0 = *(const float4*)(gB + k0);
                rb1 = *(const float4*)(gB + k0 + 4);
            }
        }

        // consume slice it from LDS[b]
        const uint16_t* aS = &As[b][0];
        const uint16_t* bS = symdiag ? &As[b][0] : &Bs[b][0];
        short8 af[2], bfr[4];
        #pragma unroll
        for (int mi = 0; mi < 2; ++mi)
            af[mi] = *(const short8*)&aS[(rowbase + mi * 16 + l15) * LDSS + quad * 8];
        #pragma unroll
        for (int ni = 0; ni < 4; ++ni)
            bfr[ni] = *(const short8*)&bS[(colbase + ni * 16 + l15) * LDSS + quad * 8];
        #pragma unroll
        for (int mi = 0; mi < 2; ++mi)
            #pragma unroll
            for (int ni = 0; ni < 4; ++ni)
                acc[mi][ni] = __builtin_amdgcn_mfma_f32_16x16x32_bf16(
                    af[mi], bfr[ni], acc[mi][ni], 0, 0, 0);
    }

    // ---- assemble row/col norms: reduce over the 4 staging threads per row
    sqp += __shfl_xor(sqp, 1); sqp += __shfl_xor(sqp, 2);
    if (!symdiag) { sqq += __shfl_xor(sqq, 1); sqq += __shfl_xor(sqq, 2); }
    if ((tid & 3) == 0) {
        rnorm[prow] = sqp;
        if (!symdiag) cnorm[prow] = sqq;
    }
    __syncthreads();
    const float* cn = symdiag ? rnorm : cnorm;

    // ---- fused epilogue: d = sqrt(max(x2_i + y2_j - 2 S_ij, 0)) ----
    // C/D layout: col = lane&15, row = (lane>>4)*4 + reg.
    float lsum = 0.0f;
    #pragma unroll
    for (int mi = 0; mi < 2; ++mi) {
        #pragma unroll
        for (int i = 0; i < 4; ++i) {
            const int r = rowbase + mi * 16 + quad * 4 + i;
            const float rv = rnorm[r];
            #pragma unroll
            for (int ni = 0; ni < 4; ++ni) {
                const int c = colbase + ni * 16 + l15;
                float d2 = rv + cn[c] - 2.0f * acc[mi][ni][i];
                float s = sqrtf(fmaxf(d2, 0.0f));
                if (symdiag && (r == c)) s = 0.0f;
                lsum += s;
            }
        }
    }
    #pragma unroll
    for (int off = 32; off; off >>= 1) lsum += __shfl_down(lsum, off);
    if (lane == 0) wpart[wv] = lsum;
    __syncthreads();
    if (tid == 0) {
        float bs = 0.0f;
        #pragma unroll
        for (int i = 0; i < 8; ++i) bs += wpart[i];
        atomicAdd(out, bs * (w * scale));
    }
}

// ---------------------------------------------------------------------------
extern "C" void kernel_launch(void* const* d_in, const int* in_sizes, int n_in,
                              void* d_out, int out_size, void* d_ws, size_t ws_size,
                              hipStream_t stream) {
    const float* X = (const float*)d_in[0];
    const float* Y = (const float*)d_in[1];
    const int total_elems = in_sizes[0];          // G*NPTS*DIM
    const int G = total_elems / (NPTS * DIM);     // 128

    float* out = (float*)d_out;
    hipMemsetAsync(out, 0, sizeof(float) * out_size, stream);

    const float scale = 1.0f / ((float)NPTS * (float)NPTS * (float)G);
    mmd_pipe<<<10 * G, 512, 0, stream>>>(X, Y, out, scale, G);
}

// Round 7
// 123.247 us; speedup vs baseline: 1.3562x; 1.3562x over previous
//
#include <hip/hip_runtime.h>
#include <hip/hip_bf16.h>
#include <stdint.h>
#include <string.h>

typedef __attribute__((ext_vector_type(8))) short short8;   // 8 bf16 (4 VGPRs) MFMA operand
typedef __attribute__((ext_vector_type(4))) float floatx4;  // MFMA accumulator

#define NPTS 256   // points per group
#define DIM  256   // feature dim
#define TILE 128   // output tile per block
#define BK   32    // K-step
#define NIT  (DIM / BK)          // 8 K-iterations
#define LDSS 40    // LDS row stride in bf16 elems (80 B; read pattern ~2-way = free)

// Workgroup barrier WITHOUT the vmcnt(0) drain __syncthreads() forces.
// LDS producer->consumer ordering needs only lgkmcnt(0); the in-flight global
// prefetches land in private VGPRs (compiler inserts vmcnt before their use in
// cvt8) and must NOT be drained here — that drain was the m97-style stall.
#define LDS_BARRIER() asm volatile("s_waitcnt lgkmcnt(0)\n\ts_barrier" ::: "memory")

// packed fp32->bf16 RNE convert; also accumulates squared sum of the
// ROUNDED values (consistent metric between Gram term and norms).
static __device__ __forceinline__ uint32_t cvtsq2(float a, float b, float& s) {
    __hip_bfloat162 h = __float22bfloat162_rn(float2{a, b});
    uint32_t d;
    memcpy(&d, &h, 4);
    const float lo = __builtin_bit_cast(float, d << 16);
    const float hi = __builtin_bit_cast(float, d & 0xFFFF0000u);
    s += lo * lo + hi * hi;
    return d;
}
static __device__ __forceinline__ uint4 cvt8(const float4 u, const float4 v, float& s) {
    uint4 r;
    r.x = cvtsq2(u.x, u.y, s); r.y = cvtsq2(u.z, u.w, s);
    r.z = cvtsq2(v.x, v.y, s); r.w = cvtsq2(v.z, v.w, s);
    return r;
}

// ---------------------------------------------------------------------------
// grid = 10*G linear blocks, XCD-swizzled so all 10 tiles of a group share an
// XCD (L2 reuse). t 0..3 = XY (w=+1), 4..6 = XX upper-tri (w=-0.5/-1/-0.5,
// off-diag tile double-counted via w), 7..9 = YY upper-tri.
// NOTE: no symdiag load-skip — round 6 showed conditionally-live prefetch
// registers inside the unrolled asm-barrier loop get demoted to scratch
// (102 MB spill traffic). Unconditional B-side keeps liveness spill-free.
// ---------------------------------------------------------------------------
__global__ __launch_bounds__(512, 4)
void mmd_pipe(const float* __restrict__ X, const float* __restrict__ Y,
              float* __restrict__ out, float scale, int G) {
    // ---- block -> (group, tile) decode with XCD swizzle ----
    int g, t;
    const int f = blockIdx.x;
    if ((G & 7) == 0) { const int xcd = f & 7, j = f >> 3; g = (j / 10) * 8 + xcd; t = j % 10; }
    else              { g = f / 10; t = f % 10; }

    int ptype, ti, tj; float w;
    if (t < 4)      { ptype = 0; ti = t >> 1; tj = t & 1; w = 1.0f; }
    else if (t < 7) { int u = t - 4; ptype = 1; ti = (u == 2); tj = (u >= 1); w = (u == 1) ? -1.0f : -0.5f; }
    else            { int u = t - 7; ptype = 2; ti = (u == 2); tj = (u >= 1); w = (u == 1) ? -1.0f : -0.5f; }

    const float *Pf, *Qf;
    if (ptype == 0)      { Pf = X; Qf = Y; }
    else if (ptype == 1) { Pf = X; Qf = X; }
    else                 { Pf = Y; Qf = Y; }
    const bool symdiag = (ptype != 0) && (ti == tj);

    const size_t prow0 = (size_t)g * NPTS + (size_t)ti * TILE;
    const size_t qrow0 = (size_t)g * NPTS + (size_t)tj * TILE;

    __shared__ __align__(16) uint16_t As[2][TILE * LDSS];  // 2 x 10 KB
    __shared__ __align__(16) uint16_t Bs[2][TILE * LDSS];
    __shared__ float rnorm[TILE];
    __shared__ float cnorm[TILE];
    __shared__ float wpart[8];

    const int tid  = threadIdx.x;          // 0..511
    const int lane = tid & 63;
    const int wv   = tid >> 6;             // 0..7
    const int quad = lane >> 4;
    const int l15  = lane & 15;
    const int rowbase = (wv & 3) * 32;     // wave's 32-row stripe
    const int colbase = (wv >> 2) * 64;    // wave's 64-col stripe

    // ---- producer geometry: thread t stages row t>>2, float cols (t&3)*8..+8
    const int prow = tid >> 2;
    const int pcol = (tid & 3) * 8;
    const float* gA = Pf + (prow0 + prow) * DIM + pcol;
    const float* gB = Qf + (qrow0 + prow) * DIM + pcol;
    const int woff = prow * LDSS + pcol;   // bf16-elem offset in LDS slice

    floatx4 acc[2][4];
    #pragma unroll
    for (int i = 0; i < 2; ++i)
        #pragma unroll
        for (int j = 0; j < 4; ++j) acc[i][j] = (floatx4)0.0f;

    float sqp = 0.0f, sqq = 0.0f;          // this thread's partial row norms

    // ---- prologue: slice 0 -> LDS[0]; start loading slice 1 ----
    float4 ra0 = *(const float4*)(gA);
    float4 ra1 = *(const float4*)(gA + 4);
    float4 rb0 = *(const float4*)(gB);
    float4 rb1 = *(const float4*)(gB + 4);
    {
        const uint4 pa = cvt8(ra0, ra1, sqp);
        const uint4 pb = cvt8(rb0, rb1, sqq);
        *(uint4*)&As[0][woff] = pa;
        *(uint4*)&Bs[0][woff] = pb;
    }
    ra0 = *(const float4*)(gA + BK);
    ra1 = *(const float4*)(gA + BK + 4);
    rb0 = *(const float4*)(gB + BK);
    rb1 = *(const float4*)(gB + BK + 4);

    // ---- main pipeline: 1 lgkm-only barrier/iter, write-ahead-1, load-ahead-2
    #pragma unroll
    for (int it = 0; it < NIT; ++it) {
        const int b = it & 1;
        LDS_BARRIER();                      // LDS[b] (written last iter) visible

        if (it < NIT - 1) {                 // write slice it+1 into LDS[b^1]
            const uint4 pa = cvt8(ra0, ra1, sqp);
            const uint4 pb = cvt8(rb0, rb1, sqq);
            *(uint4*)&As[b ^ 1][woff] = pa;
            *(uint4*)&Bs[b ^ 1][woff] = pb;
        }
        if (it < NIT - 2) {                 // start loading slice it+2
            const int k0 = (it + 2) * BK;
            ra0 = *(const float4*)(gA + k0);
            ra1 = *(const float4*)(gA + k0 + 4);
            rb0 = *(const float4*)(gB + k0);
            rb1 = *(const float4*)(gB + k0 + 4);
        }

        // consume slice it from LDS[b]
        short8 af[2], bfr[4];
        #pragma unroll
        for (int mi = 0; mi < 2; ++mi)
            af[mi] = *(const short8*)&As[b][(rowbase + mi * 16 + l15) * LDSS + quad * 8];
        #pragma unroll
        for (int ni = 0; ni < 4; ++ni)
            bfr[ni] = *(const short8*)&Bs[b][(colbase + ni * 16 + l15) * LDSS + quad * 8];
        #pragma unroll
        for (int mi = 0; mi < 2; ++mi)
            #pragma unroll
            for (int ni = 0; ni < 4; ++ni)
                acc[mi][ni] = __builtin_amdgcn_mfma_f32_16x16x32_bf16(
                    af[mi], bfr[ni], acc[mi][ni], 0, 0, 0);
    }

    // ---- assemble row/col norms: reduce over the 4 staging threads per row
    sqp += __shfl_xor(sqp, 1); sqp += __shfl_xor(sqp, 2);
    sqq += __shfl_xor(sqq, 1); sqq += __shfl_xor(sqq, 2);
    if ((tid & 3) == 0) { rnorm[prow] = sqp; cnorm[prow] = sqq; }
    __syncthreads();

    // ---- fused epilogue: d = sqrt(max(x2_i + y2_j - 2 S_ij, 0)) ----
    // C/D layout: col = lane&15, row = (lane>>4)*4 + reg.
    float lsum = 0.0f;
    #pragma unroll
    for (int mi = 0; mi < 2; ++mi) {
        #pragma unroll
        for (int i = 0; i < 4; ++i) {
            const int r = rowbase + mi * 16 + quad * 4 + i;
            const float rv = rnorm[r];
            #pragma unroll
            for (int ni = 0; ni < 4; ++ni) {
                const int c = colbase + ni * 16 + l15;
                float d2 = rv + cnorm[c] - 2.0f * acc[mi][ni][i];
                float s = sqrtf(fmaxf(d2, 0.0f));
                if (symdiag && (r == c)) s = 0.0f;
                lsum += s;
            }
        }
    }
    #pragma unroll
    for (int off = 32; off; off >>= 1) lsum += __shfl_down(lsum, off);
    if (lane == 0) wpart[wv] = lsum;
    __syncthreads();
    if (tid == 0) {
        float bs = 0.0f;
        #pragma unroll
        for (int i = 0; i < 8; ++i) bs += wpart[i];
        atomicAdd(out, bs * (w * scale));
    }
}

// ---------------------------------------------------------------------------
extern "C" void kernel_launch(void* const* d_in, const int* in_sizes, int n_in,
                              void* d_out, int out_size, void* d_ws, size_t ws_size,
                              hipStream_t stream) {
    const float* X = (const float*)d_in[0];
    const float* Y = (const float*)d_in[1];
    const int total_elems = in_sizes[0];          // G*NPTS*DIM
    const int G = total_elems / (NPTS * DIM);     // 128

    float* out = (float*)d_out;
    hipMemsetAsync(out, 0, sizeof(float) * out_size, stream);

    const float scale = 1.0f / ((float)NPTS * (float)NPTS * (float)G);
    mmd_pipe<<<10 * G, 512, 0, stream>>>(X, Y, out, scale, G);
}